// Round 2
// baseline (301.650 us; speedup 1.0000x reference)
//
#include <hip/hip_runtime.h>

#define T_ 1024
#define N_ 8
#define D_ 1024
#define H_ 16
#define HD_ 64

typedef __attribute__((ext_vector_type(8))) short bf16x8;
typedef __attribute__((ext_vector_type(4))) float f32x4;
typedef __attribute__((ext_vector_type(4))) int i32x4;
typedef unsigned short u16;

__device__ __forceinline__ float bf2f(u16 u){
  union { float f; unsigned int i; } v; v.i = ((unsigned int)u) << 16; return v.f;
}
__device__ __forceinline__ u16 f2bf(float f){
  union { float f; unsigned int i; } v; v.f = f;
  unsigned int r = v.i + 0x7FFFu + ((v.i >> 16) & 1u);
  return (u16)(r >> 16);
}

// ---------------- transpose+cast Wq (D x D) -> Wqt[n][m] bf16 ----------------
__global__ __launch_bounds__(256) void k_wqt(const float* __restrict__ Wq, u16* __restrict__ Wqt){
  __shared__ float tld[64][65];
  int m0 = blockIdx.x * 64, n0 = blockIdx.y * 64;
  int col = threadIdx.x & 63, rq = threadIdx.x >> 6;
  #pragma unroll
  for (int p = 0; p < 16; ++p){
    int row = rq * 16 + p;
    tld[row][col] = Wq[(size_t)(m0 + row) * D_ + n0 + col];
  }
  __syncthreads();
  #pragma unroll
  for (int p = 0; p < 16; ++p){
    int row = rq * 16 + p;
    Wqt[(size_t)(n0 + row) * D_ + m0 + col] = f2bf(tld[col][row]);
  }
}

// ---------------- Bt[h][d][e] = (1/8) * sum_m qw[m,h,e]*vw[m,h,d]  (bf16) ----------------
__global__ __launch_bounds__(256) void k_bmat(const float* __restrict__ qw, const float* __restrict__ vw,
                                              u16* __restrict__ Bt){
  int h = blockIdx.x >> 6, e = blockIdx.x & 63;
  int d = threadIdx.x & 63, ms = threadIdx.x >> 6;
  float acc = 0.f;
  for (int m = ms; m < D_; m += 4){
    float a = qw[(size_t)(m * H_ + h) * HD_ + e];
    float b = vw[(size_t)(m * H_ + h) * HD_ + d];
    acc = fmaf(a, b, acc);
  }
  __shared__ float red[256];
  red[threadIdx.x] = acc;
  __syncthreads();
  if (threadIdx.x < 64){
    float s = red[threadIdx.x] + red[threadIdx.x + 64] + red[threadIdx.x + 128] + red[threadIdx.x + 192];
    Bt[(size_t)(h * 64 + threadIdx.x) * 64 + e] = f2bf(s * 0.125f);
  }
}

// ---------------- 128x128 bf16 MFMA GEMM, A[MxK] @ B^T (B given [N][K]) ----------------
// A_F32/B_F32: source is f32, cast to bf16 during LDS staging.
// EPI=0: scatter to qb[bh][t][d] bf16 ;  EPI=1: C f32 + bias
template<int A_F32, int B_F32, int EPI>
__global__ __launch_bounds__(256) void k_gemm(const void* __restrict__ A_, const void* __restrict__ B_,
                                              void* __restrict__ Cv, const float* __restrict__ bias,
                                              int M, int N, int K){
  int nbn = N >> 7;
  int bm = (int)blockIdx.x / nbn, bn = (int)blockIdx.x % nbn;
  int tid = threadIdx.x, lane = tid & 63, wid = tid >> 6;
  int wr = wid >> 1, wc = wid & 1, g = lane >> 4, c = lane & 15;
  __shared__ u16 As[128 * 64];
  __shared__ u16 Bs[128 * 64];
  f32x4 zero = {0.f, 0.f, 0.f, 0.f};
  f32x4 acc[4][4];
  #pragma unroll
  for (int m = 0; m < 4; ++m)
    #pragma unroll
    for (int n = 0; n < 4; ++n) acc[m][n] = zero;
  for (int kt = 0; kt < K; kt += 64){
    __syncthreads();
    #pragma unroll
    for (int p = 0; p < 4; ++p){
      int ci = tid + p * 256;
      int row = ci >> 3, c8 = ci & 7;
      if (A_F32){
        const float* A = (const float*)A_;
        const float* src = A + (size_t)(bm * 128 + row) * K + kt + c8 * 8;
        f32x4 v0 = *(const f32x4*)src;
        f32x4 v1 = *(const f32x4*)(src + 4);
        union { u16 u[8]; i32x4 v; } pk;
        #pragma unroll
        for (int j = 0; j < 4; ++j){ pk.u[j] = f2bf(v0[j]); pk.u[4 + j] = f2bf(v1[j]); }
        *(i32x4*)&As[row * 64 + c8 * 8] = pk.v;
      } else {
        const u16* A = (const u16*)A_;
        *(i32x4*)&As[row * 64 + c8 * 8] = *(const i32x4*)(A + (size_t)(bm * 128 + row) * K + kt + c8 * 8);
      }
      if (B_F32){
        const float* B = (const float*)B_;
        const float* src = B + (size_t)(bn * 128 + row) * K + kt + c8 * 8;
        f32x4 v0 = *(const f32x4*)src;
        f32x4 v1 = *(const f32x4*)(src + 4);
        union { u16 u[8]; i32x4 v; } pk;
        #pragma unroll
        for (int j = 0; j < 4; ++j){ pk.u[j] = f2bf(v0[j]); pk.u[4 + j] = f2bf(v1[j]); }
        *(i32x4*)&Bs[row * 64 + c8 * 8] = pk.v;
      } else {
        const u16* B = (const u16*)B_;
        *(i32x4*)&Bs[row * 64 + c8 * 8] = *(const i32x4*)(B + (size_t)(bn * 128 + row) * K + kt + c8 * 8);
      }
    }
    __syncthreads();
    #pragma unroll
    for (int kk = 0; kk < 2; ++kk){
      bf16x8 af[4], bfr[4];
      #pragma unroll
      for (int m = 0; m < 4; ++m) af[m] = *(const bf16x8*)&As[(wr * 64 + m * 16 + c) * 64 + kk * 32 + g * 8];
      #pragma unroll
      for (int n = 0; n < 4; ++n) bfr[n] = *(const bf16x8*)&Bs[(wc * 64 + n * 16 + c) * 64 + kk * 32 + g * 8];
      #pragma unroll
      for (int m = 0; m < 4; ++m)
        #pragma unroll
        for (int n = 0; n < 4; ++n)
          acc[m][n] = __builtin_amdgcn_mfma_f32_16x16x32_bf16(af[m], bfr[n], acc[m][n], 0, 0, 0);
    }
  }
  #pragma unroll
  for (int m = 0; m < 4; ++m)
    #pragma unroll
    for (int n = 0; n < 4; ++n)
      #pragma unroll
      for (int r = 0; r < 4; ++r){
        int row = bm * 128 + wr * 64 + m * 16 + g * 4 + r;
        int col = bn * 128 + wc * 64 + n * 16 + c;
        float v = acc[m][n][r];
        if (EPI == 0){
          int t = row >> 3, b = row & 7, hh = col >> 6, dd = col & 63;
          ((u16*)Cv)[(((size_t)(b * H_ + hh)) * T_ + t) * HD_ + dd] = f2bf(v);
        } else {
          ((float*)Cv)[(size_t)row * N + col] = v + bias[col];
        }
      }
}

// ---------------- u^T = B_h^T q^T per (bh, 64-t tile); also q_sq. 1 wave. ----------------
__global__ __launch_bounds__(64) void k_u(const u16* __restrict__ qb, const u16* __restrict__ Bt,
                                          u16* __restrict__ ubt, float* __restrict__ qsq){
  int bh = blockIdx.x >> 4, tt = blockIdx.x & 15;
  int h = bh & 15, t0 = tt * 64;
  int lane = threadIdx.x, g = lane >> 4, c = lane & 15;
  bf16x8 af[4][2], bq[4][2];
  #pragma unroll
  for (int mf = 0; mf < 4; ++mf)
    #pragma unroll
    for (int kk = 0; kk < 2; ++kk)
      af[mf][kk] = *(const bf16x8*)(Bt + ((size_t)(h * 64 + mf * 16 + c)) * 64 + kk * 32 + g * 8);
  #pragma unroll
  for (int nf = 0; nf < 4; ++nf)
    #pragma unroll
    for (int kk = 0; kk < 2; ++kk)
      bq[nf][kk] = *(const bf16x8*)(qb + ((size_t)(bh * 1024 + t0 + nf * 16 + c)) * 64 + kk * 32 + g * 8);
  // q_sq from the same bf16 q (consistency with QK^T keeps logits exact in q~)
  #pragma unroll
  for (int nf = 0; nf < 4; ++nf){
    float ss = 0.f;
    #pragma unroll
    for (int kk = 0; kk < 2; ++kk)
      #pragma unroll
      for (int j = 0; j < 8; ++j){ float f = bf2f((u16)bq[nf][kk][j]); ss = fmaf(f, f, ss); }
    ss += __shfl_xor(ss, 16);
    ss += __shfl_xor(ss, 32);
    if (lane < 16) qsq[(size_t)bh * 1024 + t0 + nf * 16 + lane] = ss;
  }
  f32x4 zero = {0.f, 0.f, 0.f, 0.f};
  f32x4 acc[4][4];
  #pragma unroll
  for (int mf = 0; mf < 4; ++mf)
    #pragma unroll
    for (int nf = 0; nf < 4; ++nf) acc[mf][nf] = zero;
  #pragma unroll
  for (int kk = 0; kk < 2; ++kk)
    #pragma unroll
    for (int mf = 0; mf < 4; ++mf)
      #pragma unroll
      for (int nf = 0; nf < 4; ++nf)
        acc[mf][nf] = __builtin_amdgcn_mfma_f32_16x16x32_bf16(af[mf][kk], bq[nf][kk], acc[mf][nf], 0, 0, 0);
  #pragma unroll
  for (int mf = 0; mf < 4; ++mf)
    #pragma unroll
    for (int nf = 0; nf < 4; ++nf)
      #pragma unroll
      for (int r = 0; r < 4; ++r)
        ubt[((size_t)(bh * 64 + mf * 16 + g * 4 + r)) * 1024 + t0 + nf * 16 + c] = f2bf(acc[mf][nf][r]);
}

// ---------------- flash-style L2 attention per (bh, 64-row t tile) ----------------
__global__ __launch_bounds__(256) void k_attn(const u16* __restrict__ qb, const u16* __restrict__ ubt,
                                              const float* __restrict__ qsq, u16* __restrict__ obm){
  int bh = blockIdx.x >> 4, tt = blockIdx.x & 15;
  int b = bh >> 4, h = bh & 15;
  int tid = threadIdx.x, w = tid >> 6, lane = tid & 63;
  int g = lane >> 4, c = lane & 15;
  __shared__ u16 Klds[64 * 72];
  __shared__ u16 Ulds[64 * 72];
  __shared__ u16 Plds[4][16 * 72];
  const float L2E = 1.44269504088896340736f;
  int trow = tt * 64 + w * 16 + c;
  const u16* qrow = qb + ((size_t)bh * 1024 + trow) * 64;
  bf16x8 qa0 = *(const bf16x8*)(qrow + g * 8);
  bf16x8 qa1 = *(const bf16x8*)(qrow + 32 + g * 8);
  float m_r[4], l_r[4];
  f32x4 zero = {0.f, 0.f, 0.f, 0.f};
  f32x4 o_[4];
  #pragma unroll
  for (int r = 0; r < 4; ++r){ m_r[r] = -3.0e38f; l_r[r] = 0.f; }
  #pragma unroll
  for (int nf = 0; nf < 4; ++nf) o_[nf] = zero;
  for (int st = 0; st < 16; ++st){
    int s0 = st * 64;
    __syncthreads();
    #pragma unroll
    for (int p = 0; p < 2; ++p){
      int ci = tid + p * 256;
      int row = ci >> 3, c8 = ci & 7;
      *(i32x4*)&Klds[row * 72 + c8 * 8] = *(const i32x4*)(qb + ((size_t)bh * 1024 + s0 + row) * 64 + c8 * 8);
      *(i32x4*)&Ulds[row * 72 + c8 * 8] = *(const i32x4*)(ubt + ((size_t)(bh * 64 + row)) * 1024 + s0 + c8 * 8);
    }
    __syncthreads();
    float qs_[4];
    #pragma unroll
    for (int nf = 0; nf < 4; ++nf) qs_[nf] = qsq[(size_t)bh * 1024 + s0 + nf * 16 + c];
    f32x4 sf[4];
    #pragma unroll
    for (int nf = 0; nf < 4; ++nf) sf[nf] = zero;
    #pragma unroll
    for (int nf = 0; nf < 4; ++nf){
      bf16x8 kf0 = *(const bf16x8*)&Klds[(nf * 16 + c) * 72 + g * 8];
      bf16x8 kf1 = *(const bf16x8*)&Klds[(nf * 16 + c) * 72 + 32 + g * 8];
      sf[nf] = __builtin_amdgcn_mfma_f32_16x16x32_bf16(qa0, kf0, sf[nf], 0, 0, 0);
      sf[nf] = __builtin_amdgcn_mfma_f32_16x16x32_bf16(qa1, kf1, sf[nf], 0, 0, 0);
    }
    float lt[4][4];
    #pragma unroll
    for (int nf = 0; nf < 4; ++nf)
      #pragma unroll
      for (int r = 0; r < 4; ++r)
        lt[nf][r] = sf[nf][r] * 0.25f - qs_[nf] * 0.125f;
    float mt[4];
    #pragma unroll
    for (int r = 0; r < 4; ++r)
      mt[r] = fmaxf(fmaxf(lt[0][r], lt[1][r]), fmaxf(lt[2][r], lt[3][r]));
    #pragma unroll
    for (int r = 0; r < 4; ++r){
      mt[r] = fmaxf(mt[r], __shfl_xor(mt[r], 1));
      mt[r] = fmaxf(mt[r], __shfl_xor(mt[r], 2));
      mt[r] = fmaxf(mt[r], __shfl_xor(mt[r], 4));
      mt[r] = fmaxf(mt[r], __shfl_xor(mt[r], 8));
    }
    float al[4];
    #pragma unroll
    for (int r = 0; r < 4; ++r){
      float mn = fmaxf(m_r[r], mt[r]);
      al[r] = exp2f((m_r[r] - mn) * L2E);
      m_r[r] = mn;
    }
    float ps[4][4]; float rs[4] = {0.f, 0.f, 0.f, 0.f};
    #pragma unroll
    for (int nf = 0; nf < 4; ++nf)
      #pragma unroll
      for (int r = 0; r < 4; ++r){
        float p = exp2f((lt[nf][r] - m_r[r]) * L2E);
        ps[nf][r] = p; rs[r] += p;
      }
    #pragma unroll
    for (int r = 0; r < 4; ++r){
      rs[r] += __shfl_xor(rs[r], 1);
      rs[r] += __shfl_xor(rs[r], 2);
      rs[r] += __shfl_xor(rs[r], 4);
      rs[r] += __shfl_xor(rs[r], 8);
      l_r[r] = l_r[r] * al[r] + rs[r];
    }
    #pragma unroll
    for (int nf = 0; nf < 4; ++nf)
      #pragma unroll
      for (int r = 0; r < 4; ++r)
        o_[nf][r] *= al[r];
    #pragma unroll
    for (int nf = 0; nf < 4; ++nf)
      #pragma unroll
      for (int r = 0; r < 4; ++r)
        Plds[w][(g * 4 + r) * 72 + nf * 16 + c] = f2bf(ps[nf][r]);
    #pragma unroll
    for (int kk = 0; kk < 2; ++kk){
      bf16x8 pa = *(const bf16x8*)&Plds[w][c * 72 + kk * 32 + g * 8];
      #pragma unroll
      for (int nf = 0; nf < 4; ++nf){
        bf16x8 uf = *(const bf16x8*)&Ulds[(nf * 16 + c) * 72 + kk * 32 + g * 8];
        o_[nf] = __builtin_amdgcn_mfma_f32_16x16x32_bf16(pa, uf, o_[nf], 0, 0, 0);
      }
    }
  }
  #pragma unroll
  for (int nf = 0; nf < 4; ++nf)
    #pragma unroll
    for (int r = 0; r < 4; ++r){
      int t = tt * 64 + w * 16 + g * 4 + r;
      int dd = nf * 16 + c;
      obm[((size_t)(t * 8 + b)) * 1024 + h * 64 + dd] = f2bf(o_[nf][r] / l_r[r]);
    }
}

extern "C" void kernel_launch(void* const* d_in, const int* in_sizes, int n_in,
                              void* d_out, int out_size, void* d_ws, size_t ws_size,
                              hipStream_t stream) {
  const float* x   = (const float*)d_in[0];
  const float* qw  = (const float*)d_in[1];
  const float* vw  = (const float*)d_in[2];
  const float* ow  = (const float*)d_in[3];
  const float* ob_bias = (const float*)d_in[4];
  float* out = (float*)d_out;

  // d_out (32 MiB) doubles as scratch for qb + ubt; both are dead before the
  // final GEMM overwrites d_out with the result.
  u16* qb  = (u16*)d_out;                                   // [bh][t][d]  16 MiB
  u16* ubt = (u16*)((char*)d_out + (size_t)16 * 1024 * 1024); // [bh][d][t] 16 MiB

  char* ws = (char*)d_ws;
  size_t off = 0;
  auto alloc = [&](size_t bytes) -> void* {
    void* p = ws + off;
    off += (bytes + 255) & ~(size_t)255;
    return p;
  };
  u16*   wqt = (u16*)  alloc((size_t)1024 * 1024 * 2);   // Wq^T bf16 [n][m]   2 MiB
  u16*   obm = (u16*)  alloc((size_t)8192 * 1024 * 2);   // attn out bf16     16 MiB
  float* qsq = (float*)alloc((size_t)128 * 1024 * 4);    // |q|^2 [bh][t]    0.5 MiB
  u16*   Bt  = (u16*)  alloc((size_t)16 * 64 * 64 * 2);  // B_h^T bf16      0.125 MiB

  k_wqt<<<dim3(16, 16), 256, 0, stream>>>(qw, wqt);
  k_bmat<<<1024, 256, 0, stream>>>(qw, vw, Bt);
  // GEMM1: q = x @ Wq  (A = x f32 cast-on-stage, B = Wq^T bf16) -> qb scatter
  k_gemm<1, 0, 0><<<512, 256, 0, stream>>>(x, wqt, qb, nullptr, 8192, 1024, 1024);
  k_u<<<2048, 64, 0, stream>>>(qb, Bt, ubt, qsq);
  k_attn<<<2048, 256, 0, stream>>>(qb, ubt, qsq, obm);
  // GEMM2: out = obm @ out_w^T + b  (A = obm bf16, B = out_w f32 cast-on-stage)
  k_gemm<0, 1, 1><<<512, 256, 0, stream>>>(obm, ow, out, ob_bias, 8192, 1024, 1024);
}

// Round 3
// 231.899 us; speedup vs baseline: 1.3008x; 1.3008x over previous
//
#include <hip/hip_runtime.h>
#include <hip/hip_bf16.h>

#define T_ 1024
#define N_ 8
#define D_ 1024
#define H_ 16
#define HD_ 64

typedef __attribute__((ext_vector_type(8))) short bf16x8;
typedef __attribute__((ext_vector_type(4))) float f32x4;
typedef __attribute__((ext_vector_type(4))) int i32x4;
typedef unsigned short u16;

__device__ __forceinline__ float bf2f(u16 u){
  union { float f; unsigned int i; } v; v.i = ((unsigned int)u) << 16; return v.f;
}
__device__ __forceinline__ u16 f2bf(float f){
  union { float f; unsigned int i; } v; v.f = f;
  unsigned int r = v.i + 0x7FFFu + ((v.i >> 16) & 1u);
  return (u16)(r >> 16);
}
__device__ __forceinline__ u16 f2bf_fast(float f){
  __hip_bfloat16 h = __float2bfloat16(f);   // RNE; compiler can pack pairs into v_cvt_pk_bf16_f32
  return *reinterpret_cast<u16*>(&h);
}

// ---------------- transpose+cast Wq (D x D) -> Wqt[n][m] bf16 ----------------
__global__ __launch_bounds__(256) void k_wqt(const float* __restrict__ Wq, u16* __restrict__ Wqt){
  __shared__ float tld[64][65];
  int m0 = blockIdx.x * 64, n0 = blockIdx.y * 64;
  int col = threadIdx.x & 63, rq = threadIdx.x >> 6;
  #pragma unroll
  for (int p = 0; p < 16; ++p){
    int row = rq * 16 + p;
    tld[row][col] = Wq[(size_t)(m0 + row) * D_ + n0 + col];
  }
  __syncthreads();
  #pragma unroll
  for (int p = 0; p < 16; ++p){
    int row = rq * 16 + p;
    Wqt[(size_t)(n0 + row) * D_ + m0 + col] = f2bf(tld[col][row]);
  }
}

// ---------------- Bt[h][d][e] = (1/8) * sum_m qw[m,h,e]*vw[m,h,d]  (bf16) ----------------
__global__ __launch_bounds__(256) void k_bmat(const float* __restrict__ qw, const float* __restrict__ vw,
                                              u16* __restrict__ Bt){
  int h = blockIdx.x >> 6, e = blockIdx.x & 63;
  int d = threadIdx.x & 63, ms = threadIdx.x >> 6;
  float acc = 0.f;
  for (int m = ms; m < D_; m += 4){
    float a = qw[(size_t)(m * H_ + h) * HD_ + e];
    float b = vw[(size_t)(m * H_ + h) * HD_ + d];
    acc = fmaf(a, b, acc);
  }
  __shared__ float red[256];
  red[threadIdx.x] = acc;
  __syncthreads();
  if (threadIdx.x < 64){
    float s = red[threadIdx.x] + red[threadIdx.x + 64] + red[threadIdx.x + 128] + red[threadIdx.x + 192];
    Bt[(size_t)(h * 64 + threadIdx.x) * 64 + e] = f2bf(s * 0.125f);
  }
}

// swizzled u16-index within a [rows][64] u16 LDS tile: XOR byte-bits 4-6 with row&7
__device__ __forceinline__ int swz(int row, int colbyte){
  return row * 64 + (((colbyte) ^ ((row & 7) << 4)) >> 1);
}

// ---------------- 128x128 bf16 MFMA GEMM, A[MxK] @ B^T (B given [N][K]) ----------------
// A_F32/B_F32: source is f32, cast to bf16 during LDS staging.
// EPI=0: scatter to qb[bh][t][d] bf16 ;  EPI=1: C f32 + bias
template<int A_F32, int B_F32, int EPI>
__global__ __launch_bounds__(256) void k_gemm(const void* __restrict__ A_, const void* __restrict__ B_,
                                              void* __restrict__ Cv, const float* __restrict__ bias,
                                              int M, int N, int K){
  int nbn = N >> 7;
  int ii = (int)blockIdx.x;
  int sw = (ii & 7) * 64 + (ii >> 3);      // XCD-contiguous chunks (512 = 8*64 blocks)
  int bm = sw / nbn, bn = sw % nbn;
  int tid = threadIdx.x, lane = tid & 63, wid = tid >> 6;
  int wr = wid >> 1, wc = wid & 1, g = lane >> 4, c = lane & 15;
  __shared__ u16 As[128 * 64];
  __shared__ u16 Bs[128 * 64];
  f32x4 zero = {0.f, 0.f, 0.f, 0.f};
  f32x4 acc[4][4];
  #pragma unroll
  for (int m = 0; m < 4; ++m)
    #pragma unroll
    for (int n = 0; n < 4; ++n) acc[m][n] = zero;
  for (int kt = 0; kt < K; kt += 64){
    __syncthreads();
    #pragma unroll
    for (int p = 0; p < 4; ++p){
      int ci = tid + p * 256;
      int row = ci >> 3, c8 = ci & 7;
      int dst = swz(row, c8 * 16);
      if (A_F32){
        const float* A = (const float*)A_;
        const float* src = A + (size_t)(bm * 128 + row) * K + kt + c8 * 8;
        f32x4 v0 = *(const f32x4*)src;
        f32x4 v1 = *(const f32x4*)(src + 4);
        union { u16 u[8]; i32x4 v; } pk;
        #pragma unroll
        for (int j = 0; j < 4; ++j){ pk.u[j] = f2bf_fast(v0[j]); pk.u[4 + j] = f2bf_fast(v1[j]); }
        *(i32x4*)&As[dst] = pk.v;
      } else {
        const u16* A = (const u16*)A_;
        *(i32x4*)&As[dst] = *(const i32x4*)(A + (size_t)(bm * 128 + row) * K + kt + c8 * 8);
      }
      if (B_F32){
        const float* B = (const float*)B_;
        const float* src = B + (size_t)(bn * 128 + row) * K + kt + c8 * 8;
        f32x4 v0 = *(const f32x4*)src;
        f32x4 v1 = *(const f32x4*)(src + 4);
        union { u16 u[8]; i32x4 v; } pk;
        #pragma unroll
        for (int j = 0; j < 4; ++j){ pk.u[j] = f2bf_fast(v0[j]); pk.u[4 + j] = f2bf_fast(v1[j]); }
        *(i32x4*)&Bs[dst] = pk.v;
      } else {
        const u16* B = (const u16*)B_;
        *(i32x4*)&Bs[dst] = *(const i32x4*)(B + (size_t)(bn * 128 + row) * K + kt + c8 * 8);
      }
    }
    __syncthreads();
    #pragma unroll
    for (int kk = 0; kk < 2; ++kk){
      bf16x8 af[4], bfr[4];
      #pragma unroll
      for (int m = 0; m < 4; ++m){
        int row = wr * 64 + m * 16 + c;
        af[m] = *(const bf16x8*)&As[swz(row, kk * 64 + g * 16)];
      }
      #pragma unroll
      for (int n = 0; n < 4; ++n){
        int row = wc * 64 + n * 16 + c;
        bfr[n] = *(const bf16x8*)&Bs[swz(row, kk * 64 + g * 16)];
      }
      #pragma unroll
      for (int m = 0; m < 4; ++m)
        #pragma unroll
        for (int n = 0; n < 4; ++n)
          acc[m][n] = __builtin_amdgcn_mfma_f32_16x16x32_bf16(af[m], bfr[n], acc[m][n], 0, 0, 0);
    }
  }
  #pragma unroll
  for (int m = 0; m < 4; ++m)
    #pragma unroll
    for (int n = 0; n < 4; ++n)
      #pragma unroll
      for (int r = 0; r < 4; ++r){
        int row = bm * 128 + wr * 64 + m * 16 + g * 4 + r;
        int col = bn * 128 + wc * 64 + n * 16 + c;
        float v = acc[m][n][r];
        if (EPI == 0){
          int t = row >> 3, b = row & 7, hh = col >> 6, dd = col & 63;
          ((u16*)Cv)[(((size_t)(b * H_ + hh)) * T_ + t) * HD_ + dd] = f2bf(v);
        } else {
          ((float*)Cv)[(size_t)row * N + col] = v + bias[col];
        }
      }
}

// ---------------- u^T = B_h^T q^T per (bh, 64-t tile); also q_sq. 1 wave. ----------------
__global__ __launch_bounds__(64) void k_u(const u16* __restrict__ qb, const u16* __restrict__ Bt,
                                          u16* __restrict__ ubt, float* __restrict__ qsq){
  int bh = blockIdx.x >> 4, tt = blockIdx.x & 15;
  int h = bh & 15, t0 = tt * 64;
  int lane = threadIdx.x, g = lane >> 4, c = lane & 15;
  bf16x8 af[4][2], bq[4][2];
  #pragma unroll
  for (int mf = 0; mf < 4; ++mf)
    #pragma unroll
    for (int kk = 0; kk < 2; ++kk)
      af[mf][kk] = *(const bf16x8*)(Bt + ((size_t)(h * 64 + mf * 16 + c)) * 64 + kk * 32 + g * 8);
  #pragma unroll
  for (int nf = 0; nf < 4; ++nf)
    #pragma unroll
    for (int kk = 0; kk < 2; ++kk)
      bq[nf][kk] = *(const bf16x8*)(qb + ((size_t)(bh * 1024 + t0 + nf * 16 + c)) * 64 + kk * 32 + g * 8);
  // q_sq from the same bf16 q (consistency with QK^T keeps logits exact in q~)
  #pragma unroll
  for (int nf = 0; nf < 4; ++nf){
    float ss = 0.f;
    #pragma unroll
    for (int kk = 0; kk < 2; ++kk)
      #pragma unroll
      for (int j = 0; j < 8; ++j){ float f = bf2f((u16)bq[nf][kk][j]); ss = fmaf(f, f, ss); }
    ss += __shfl_xor(ss, 16);
    ss += __shfl_xor(ss, 32);
    if (lane < 16) qsq[(size_t)bh * 1024 + t0 + nf * 16 + lane] = ss;
  }
  f32x4 zero = {0.f, 0.f, 0.f, 0.f};
  f32x4 acc[4][4];
  #pragma unroll
  for (int mf = 0; mf < 4; ++mf)
    #pragma unroll
    for (int nf = 0; nf < 4; ++nf) acc[mf][nf] = zero;
  #pragma unroll
  for (int kk = 0; kk < 2; ++kk)
    #pragma unroll
    for (int mf = 0; mf < 4; ++mf)
      #pragma unroll
      for (int nf = 0; nf < 4; ++nf)
        acc[mf][nf] = __builtin_amdgcn_mfma_f32_16x16x32_bf16(af[mf][kk], bq[nf][kk], acc[mf][nf], 0, 0, 0);
  #pragma unroll
  for (int mf = 0; mf < 4; ++mf)
    #pragma unroll
    for (int nf = 0; nf < 4; ++nf)
      #pragma unroll
      for (int r = 0; r < 4; ++r)
        ubt[((size_t)(bh * 64 + mf * 16 + g * 4 + r)) * 1024 + t0 + nf * 16 + c] = f2bf(acc[mf][nf][r]);
}

// ---------------- flash-style L2 attention, fixed-max softmax ----------------
// logits_eff = S/4 - qsq_s/8 (row max known: qsq_t/8 at s=t; row-constant scale
// 2^{qsq_t*L2E/8} cancels in o/l, so we drop it entirely).
__global__ __launch_bounds__(256) void k_attn(const u16* __restrict__ qb, const u16* __restrict__ ubt,
                                              const float* __restrict__ qsq, u16* __restrict__ obm){
  int i = (int)blockIdx.x;
  // XCD grouping: XCD (i&7) gets bh in [16*(i&7), 16*(i&7)+16), all 16 t-tiles.
  int bh = ((i & 7) << 4) + (i >> 7);
  int tt = (i >> 3) & 15;
  int b = bh >> 4, h = bh & 15;
  int tid = threadIdx.x, w = tid >> 6, lane = tid & 63;
  int g = lane >> 4, c = lane & 15;
  __shared__ u16 Klds[64 * 64];
  __shared__ u16 Ulds[64 * 64];
  __shared__ u16 Plds[4][16 * 72];
  const float L2E = 1.44269504088896340736f;
  const float C1 = 0.25f * L2E;
  int trow = tt * 64 + w * 16 + c;
  const u16* qrow = qb + ((size_t)bh * 1024 + trow) * 64;
  bf16x8 qa0 = *(const bf16x8*)(qrow + g * 8);
  bf16x8 qa1 = *(const bf16x8*)(qrow + 32 + g * 8);
  float l_r[4] = {0.f, 0.f, 0.f, 0.f};
  f32x4 zero = {0.f, 0.f, 0.f, 0.f};
  f32x4 o_[4];
  #pragma unroll
  for (int nf = 0; nf < 4; ++nf) o_[nf] = zero;
  for (int st = 0; st < 16; ++st){
    int s0 = st * 64;
    __syncthreads();
    #pragma unroll
    for (int p = 0; p < 2; ++p){
      int ci = tid + p * 256;
      int row = ci >> 3, c8 = ci & 7;
      int dst = swz(row, c8 * 16);
      *(i32x4*)&Klds[dst] = *(const i32x4*)(qb + ((size_t)bh * 1024 + s0 + row) * 64 + c8 * 8);
      *(i32x4*)&Ulds[dst] = *(const i32x4*)(ubt + ((size_t)(bh * 64 + row)) * 1024 + s0 + c8 * 8);
    }
    __syncthreads();
    float qs8[4];
    #pragma unroll
    for (int nf = 0; nf < 4; ++nf)
      qs8[nf] = qsq[(size_t)bh * 1024 + s0 + nf * 16 + c] * (0.125f * L2E);
    f32x4 sf[4];
    #pragma unroll
    for (int nf = 0; nf < 4; ++nf) sf[nf] = zero;
    #pragma unroll
    for (int nf = 0; nf < 4; ++nf){
      int krow = nf * 16 + c;
      bf16x8 kf0 = *(const bf16x8*)&Klds[swz(krow, g * 16)];
      bf16x8 kf1 = *(const bf16x8*)&Klds[swz(krow, 64 + g * 16)];
      sf[nf] = __builtin_amdgcn_mfma_f32_16x16x32_bf16(qa0, kf0, sf[nf], 0, 0, 0);
      sf[nf] = __builtin_amdgcn_mfma_f32_16x16x32_bf16(qa1, kf1, sf[nf], 0, 0, 0);
    }
    // p' = 2^(S*C1 - qs8); row-max bounded (<= 2^(qsq_t/8*L2E) ~ e^15 worst case)
    #pragma unroll
    for (int nf = 0; nf < 4; ++nf)
      #pragma unroll
      for (int r = 0; r < 4; ++r){
        float p = exp2f(fmaf(sf[nf][r], C1, -qs8[nf]));
        l_r[r] += p;
        Plds[w][(g * 4 + r) * 72 + nf * 16 + c] = f2bf_fast(p);
      }
    #pragma unroll
    for (int kk = 0; kk < 2; ++kk){
      bf16x8 pa = *(const bf16x8*)&Plds[w][c * 72 + kk * 32 + g * 8];
      #pragma unroll
      for (int nf = 0; nf < 4; ++nf){
        int urow = nf * 16 + c;
        bf16x8 uf = *(const bf16x8*)&Ulds[swz(urow, kk * 64 + g * 16)];
        o_[nf] = __builtin_amdgcn_mfma_f32_16x16x32_bf16(pa, uf, o_[nf], 0, 0, 0);
      }
    }
  }
  // one deferred row-sum reduce across the 16 c-lanes
  #pragma unroll
  for (int r = 0; r < 4; ++r){
    l_r[r] += __shfl_xor(l_r[r], 1);
    l_r[r] += __shfl_xor(l_r[r], 2);
    l_r[r] += __shfl_xor(l_r[r], 4);
    l_r[r] += __shfl_xor(l_r[r], 8);
  }
  #pragma unroll
  for (int nf = 0; nf < 4; ++nf)
    #pragma unroll
    for (int r = 0; r < 4; ++r){
      int t = tt * 64 + w * 16 + g * 4 + r;
      int dd = nf * 16 + c;
      obm[((size_t)(t * 8 + b)) * 1024 + h * 64 + dd] = f2bf(o_[nf][r] / l_r[r]);
    }
}

extern "C" void kernel_launch(void* const* d_in, const int* in_sizes, int n_in,
                              void* d_out, int out_size, void* d_ws, size_t ws_size,
                              hipStream_t stream) {
  const float* x   = (const float*)d_in[0];
  const float* qw  = (const float*)d_in[1];
  const float* vw  = (const float*)d_in[2];
  const float* ow  = (const float*)d_in[3];
  const float* ob_bias = (const float*)d_in[4];
  float* out = (float*)d_out;

  // d_out (32 MiB) doubles as scratch for qb + ubt; both are dead before the
  // final GEMM overwrites d_out with the result.
  u16* qb  = (u16*)d_out;                                     // [bh][t][d]  16 MiB
  u16* ubt = (u16*)((char*)d_out + (size_t)16 * 1024 * 1024); // [bh][d][t]  16 MiB

  char* ws = (char*)d_ws;
  size_t off = 0;
  auto alloc = [&](size_t bytes) -> void* {
    void* p = ws + off;
    off += (bytes + 255) & ~(size_t)255;
    return p;
  };
  u16*   wqt = (u16*)  alloc((size_t)1024 * 1024 * 2);   // Wq^T bf16 [n][m]   2 MiB
  u16*   obm = (u16*)  alloc((size_t)8192 * 1024 * 2);   // attn out bf16     16 MiB
  float* qsq = (float*)alloc((size_t)128 * 1024 * 4);    // |q|^2 [bh][t]    0.5 MiB
  u16*   Bt  = (u16*)  alloc((size_t)16 * 64 * 64 * 2);  // B_h^T bf16      0.125 MiB

  k_wqt<<<dim3(16, 16), 256, 0, stream>>>(qw, wqt);
  k_bmat<<<1024, 256, 0, stream>>>(qw, vw, Bt);
  // GEMM1: q = x @ Wq  (A = x f32 cast-on-stage, B = Wq^T bf16) -> qb scatter
  k_gemm<1, 0, 0><<<512, 256, 0, stream>>>(x, wqt, qb, nullptr, 8192, 1024, 1024);
  k_u<<<2048, 64, 0, stream>>>(qb, Bt, ubt, qsq);
  k_attn<<<2048, 256, 0, stream>>>(qb, ubt, qsq, obm);
  // GEMM2: out = obm @ out_w^T + b  (A = obm bf16, B = out_w f32 cast-on-stage)
  k_gemm<0, 1, 1><<<512, 256, 0, stream>>>(obm, ow, out, ob_bias, 8192, 1024, 1024);
}

// Round 4
// 156.173 us; speedup vs baseline: 1.9315x; 1.4849x over previous
//
#include <hip/hip_runtime.h>
#include <hip/hip_bf16.h>

#define T_ 1024
#define N_ 8
#define D_ 1024
#define H_ 16
#define HD_ 64

typedef __attribute__((ext_vector_type(8))) short bf16x8;
typedef __attribute__((ext_vector_type(4))) float f32x4;
typedef __attribute__((ext_vector_type(4))) int i32x4;
typedef __attribute__((ext_vector_type(2))) unsigned int u32x2;
typedef unsigned short u16;
typedef unsigned int u32;

__device__ __forceinline__ float bf2f(u16 u){
  union { float f; unsigned int i; } v; v.i = ((unsigned int)u) << 16; return v.f;
}
__device__ __forceinline__ u16 f2bf(float f){
  union { float f; unsigned int i; } v; v.f = f;
  unsigned int r = v.i + 0x7FFFu + ((v.i >> 16) & 1u);
  return (u16)(r >> 16);
}
__device__ __forceinline__ u16 f2bf_fast(float f){
  __hip_bfloat16 h = __float2bfloat16(f);   // RNE; compiler can pack pairs into v_cvt_pk_bf16_f32
  return *reinterpret_cast<u16*>(&h);
}

// ---------------- transpose+cast Wq (D x D) -> Wqt[n][m] bf16 ----------------
__global__ __launch_bounds__(256) void k_wqt(const float* __restrict__ Wq, u16* __restrict__ Wqt){
  __shared__ float tld[64][65];
  int m0 = blockIdx.x * 64, n0 = blockIdx.y * 64;
  int col = threadIdx.x & 63, rq = threadIdx.x >> 6;
  #pragma unroll
  for (int p = 0; p < 16; ++p){
    int row = rq * 16 + p;
    tld[row][col] = Wq[(size_t)(m0 + row) * D_ + n0 + col];
  }
  __syncthreads();
  #pragma unroll
  for (int p = 0; p < 16; ++p){
    int row = rq * 16 + p;
    Wqt[(size_t)(n0 + row) * D_ + m0 + col] = f2bf(tld[col][row]);
  }
}

// ---------------- Bp[sp][h][d][e] partials of sum_m qw[m,h,e]*vw[m,h,d] (MFMA split-K) ----------------
__global__ __launch_bounds__(256) void k_bmatp(const float* __restrict__ qw, const float* __restrict__ vw,
                                               float* __restrict__ Bp){
  int h = (int)blockIdx.x >> 3, sp = (int)blockIdx.x & 7;
  int tid = threadIdx.x, lane = tid & 63, w = tid >> 6;
  int g = lane >> 4, c = lane & 15;
  __shared__ u16 Qt[64 * 72];  // [e][m] transposed, bf16
  __shared__ u16 Vt[64 * 72];  // [d][m]
  f32x4 zero = {0.f, 0.f, 0.f, 0.f};
  f32x4 acc[4];
  #pragma unroll
  for (int eb = 0; eb < 4; ++eb) acc[eb] = zero;
  int m = tid >> 2, cg = tid & 3;
  for (int mt = sp * 128; mt < sp * 128 + 128; mt += 64){
    __syncthreads();
    #pragma unroll
    for (int q = 0; q < 4; ++q){
      int e0 = cg * 16 + q * 4;
      f32x4 vq = *(const f32x4*)(qw + (size_t)(mt + m) * D_ + h * 64 + e0);
      f32x4 vv = *(const f32x4*)(vw + (size_t)(mt + m) * D_ + h * 64 + e0);
      #pragma unroll
      for (int j = 0; j < 4; ++j){
        Qt[(e0 + j) * 72 + m] = f2bf_fast(vq[j]);
        Vt[(e0 + j) * 72 + m] = f2bf_fast(vv[j]);
      }
    }
    __syncthreads();
    #pragma unroll
    for (int kk = 0; kk < 2; ++kk){
      bf16x8 av = *(const bf16x8*)&Vt[(w * 16 + c) * 72 + kk * 32 + g * 8];
      #pragma unroll
      for (int eb = 0; eb < 4; ++eb){
        bf16x8 bq = *(const bf16x8*)&Qt[(eb * 16 + c) * 72 + kk * 32 + g * 8];
        acc[eb] = __builtin_amdgcn_mfma_f32_16x16x32_bf16(av, bq, acc[eb], 0, 0, 0);
      }
    }
  }
  #pragma unroll
  for (int eb = 0; eb < 4; ++eb)
    #pragma unroll
    for (int r = 0; r < 4; ++r){
      int d = w * 16 + g * 4 + r, e = eb * 16 + c;
      Bp[(((size_t)sp * 16 + h) * 64 + d) * 64 + e] = acc[eb][r];
    }
}

// ---------------- reduce 8 partials -> Bt bf16 ----------------
__global__ __launch_bounds__(256) void k_bred(const float* __restrict__ Bp, u16* __restrict__ Bt){
  int i = blockIdx.x * 256 + threadIdx.x;   // 65536 total
  float s = 0.f;
  #pragma unroll
  for (int j = 0; j < 8; ++j) s += Bp[(size_t)j * 65536 + i];
  Bt[i] = f2bf(s * 0.125f);
}

// swizzled u16-index within a [rows][64] u16 LDS tile: XOR byte-bits 4-6 with row&7
__device__ __forceinline__ int swz(int row, int colbyte){
  return row * 64 + (((colbyte) ^ ((row & 7) << 4)) >> 1);
}

// ---------------- 128x128 bf16 MFMA GEMM, A[MxK] @ B^T (B given [N][K]) ----------------
template<int A_F32, int B_F32, int EPI>
__global__ __launch_bounds__(256) void k_gemm(const void* __restrict__ A_, const void* __restrict__ B_,
                                              void* __restrict__ Cv, const float* __restrict__ bias,
                                              int M, int N, int K){
  int nbn = N >> 7;
  int ii = (int)blockIdx.x;
  int sw = (ii & 7) * 64 + (ii >> 3);      // XCD-contiguous chunks (512 = 8*64 blocks)
  int bm = sw / nbn, bn = sw % nbn;
  int tid = threadIdx.x, lane = tid & 63, wid = tid >> 6;
  int wr = wid >> 1, wc = wid & 1, g = lane >> 4, c = lane & 15;
  __shared__ u16 As[128 * 64];
  __shared__ u16 Bs[128 * 64];
  f32x4 zero = {0.f, 0.f, 0.f, 0.f};
  f32x4 acc[4][4];
  #pragma unroll
  for (int m = 0; m < 4; ++m)
    #pragma unroll
    for (int n = 0; n < 4; ++n) acc[m][n] = zero;
  for (int kt = 0; kt < K; kt += 64){
    __syncthreads();
    #pragma unroll
    for (int p = 0; p < 4; ++p){
      int ci = tid + p * 256;
      int row = ci >> 3, c8 = ci & 7;
      int dst = swz(row, c8 * 16);
      if (A_F32){
        const float* A = (const float*)A_;
        const float* src = A + (size_t)(bm * 128 + row) * K + kt + c8 * 8;
        f32x4 v0 = *(const f32x4*)src;
        f32x4 v1 = *(const f32x4*)(src + 4);
        union { u16 u[8]; i32x4 v; } pk;
        #pragma unroll
        for (int j = 0; j < 4; ++j){ pk.u[j] = f2bf_fast(v0[j]); pk.u[4 + j] = f2bf_fast(v1[j]); }
        *(i32x4*)&As[dst] = pk.v;
      } else {
        const u16* A = (const u16*)A_;
        *(i32x4*)&As[dst] = *(const i32x4*)(A + (size_t)(bm * 128 + row) * K + kt + c8 * 8);
      }
      if (B_F32){
        const float* B = (const float*)B_;
        const float* src = B + (size_t)(bn * 128 + row) * K + kt + c8 * 8;
        f32x4 v0 = *(const f32x4*)src;
        f32x4 v1 = *(const f32x4*)(src + 4);
        union { u16 u[8]; i32x4 v; } pk;
        #pragma unroll
        for (int j = 0; j < 4; ++j){ pk.u[j] = f2bf_fast(v0[j]); pk.u[4 + j] = f2bf_fast(v1[j]); }
        *(i32x4*)&Bs[dst] = pk.v;
      } else {
        const u16* B = (const u16*)B_;
        *(i32x4*)&Bs[dst] = *(const i32x4*)(B + (size_t)(bn * 128 + row) * K + kt + c8 * 8);
      }
    }
    __syncthreads();
    #pragma unroll
    for (int kk = 0; kk < 2; ++kk){
      bf16x8 af[4], bfr[4];
      #pragma unroll
      for (int m = 0; m < 4; ++m){
        int row = wr * 64 + m * 16 + c;
        af[m] = *(const bf16x8*)&As[swz(row, kk * 64 + g * 16)];
      }
      #pragma unroll
      for (int n = 0; n < 4; ++n){
        int row = wc * 64 + n * 16 + c;
        bfr[n] = *(const bf16x8*)&Bs[swz(row, kk * 64 + g * 16)];
      }
      #pragma unroll
      for (int m = 0; m < 4; ++m)
        #pragma unroll
        for (int n = 0; n < 4; ++n)
          acc[m][n] = __builtin_amdgcn_mfma_f32_16x16x32_bf16(af[m], bfr[n], acc[m][n], 0, 0, 0);
    }
  }
  #pragma unroll
  for (int m = 0; m < 4; ++m)
    #pragma unroll
    for (int n = 0; n < 4; ++n)
      #pragma unroll
      for (int r = 0; r < 4; ++r){
        int row = bm * 128 + wr * 64 + m * 16 + g * 4 + r;
        int col = bn * 128 + wc * 64 + n * 16 + c;
        float v = acc[m][n][r];
        if (EPI == 0){
          int t = row >> 3, b = row & 7, hh = col >> 6, dd = col & 63;
          ((u16*)Cv)[(((size_t)(b * H_ + hh)) * T_ + t) * HD_ + dd] = f2bf(v);
        } else {
          ((float*)Cv)[(size_t)row * N + col] = v + bias[col];
        }
      }
}

// ---------------- u^T = B_h^T q^T per (bh, 64-t tile); also scaled q_sq. 1 wave. ----------------
__global__ __launch_bounds__(64) void k_u(const u16* __restrict__ qb, const u16* __restrict__ Bt,
                                          u16* __restrict__ ubt, float* __restrict__ qsq){
  int bh = blockIdx.x >> 4, tt = blockIdx.x & 15;
  int h = bh & 15, t0 = tt * 64;
  int lane = threadIdx.x, g = lane >> 4, c = lane & 15;
  const float QS_SCALE = 0.125f * 1.44269504088896340736f;
  bf16x8 af[4][2], bq[4][2];
  #pragma unroll
  for (int mf = 0; mf < 4; ++mf)
    #pragma unroll
    for (int kk = 0; kk < 2; ++kk)
      af[mf][kk] = *(const bf16x8*)(Bt + ((size_t)(h * 64 + mf * 16 + c)) * 64 + kk * 32 + g * 8);
  #pragma unroll
  for (int nf = 0; nf < 4; ++nf)
    #pragma unroll
    for (int kk = 0; kk < 2; ++kk)
      bq[nf][kk] = *(const bf16x8*)(qb + ((size_t)(bh * 1024 + t0 + nf * 16 + c)) * 64 + kk * 32 + g * 8);
  // q_sq from the same bf16 q; prescaled by 0.125*log2(e)
  #pragma unroll
  for (int nf = 0; nf < 4; ++nf){
    float ss = 0.f;
    #pragma unroll
    for (int kk = 0; kk < 2; ++kk)
      #pragma unroll
      for (int j = 0; j < 8; ++j){ float f = bf2f((u16)bq[nf][kk][j]); ss = fmaf(f, f, ss); }
    ss += __shfl_xor(ss, 16);
    ss += __shfl_xor(ss, 32);
    if (lane < 16) qsq[(size_t)bh * 1024 + t0 + nf * 16 + lane] = ss * QS_SCALE;
  }
  f32x4 zero = {0.f, 0.f, 0.f, 0.f};
  f32x4 acc[4][4];
  #pragma unroll
  for (int mf = 0; mf < 4; ++mf)
    #pragma unroll
    for (int nf = 0; nf < 4; ++nf) acc[mf][nf] = zero;
  #pragma unroll
  for (int kk = 0; kk < 2; ++kk)
    #pragma unroll
    for (int mf = 0; mf < 4; ++mf)
      #pragma unroll
      for (int nf = 0; nf < 4; ++nf)
        acc[mf][nf] = __builtin_amdgcn_mfma_f32_16x16x32_bf16(af[mf][kk], bq[nf][kk], acc[mf][nf], 0, 0, 0);
  #pragma unroll
  for (int mf = 0; mf < 4; ++mf)
    #pragma unroll
    for (int nf = 0; nf < 4; ++nf)
      #pragma unroll
      for (int r = 0; r < 4; ++r)
        ubt[((size_t)(bh * 64 + mf * 16 + g * 4 + r)) * 1024 + t0 + nf * 16 + c] = f2bf(acc[mf][nf][r]);
}

// ---------------- flash-style L2 attention, fixed-max softmax, swapped QK^T ----------------
// S^T = mfma(K, Q): lane (c,g) holds P[t=c][s=nf*16+g*4+r] -> l is lane-local,
// P packs to u32 pairs (cvt_pk) and stores with 4 ds_write_b64 per tile.
__global__ __launch_bounds__(256) void k_attn(const u16* __restrict__ qb, const u16* __restrict__ ubt,
                                              const float* __restrict__ qsq, u16* __restrict__ obm){
  int i = (int)blockIdx.x;
  // XCD grouping: XCD (i&7) gets bh in [16*(i&7), 16*(i&7)+16), all 16 t-tiles.
  int bh = ((i & 7) << 4) + (i >> 7);
  int tt = (i >> 3) & 15;
  int b = bh >> 4, h = bh & 15;
  int tid = threadIdx.x, w = tid >> 6, lane = tid & 63;
  int g = lane >> 4, c = lane & 15;
  __shared__ u16 Klds[64 * 64];
  __shared__ u16 Ulds[64 * 64];
  __shared__ u16 Plds[4][16 * 72];
  const float L2E = 1.44269504088896340736f;
  const float C1 = 0.25f * L2E;
  int trow = tt * 64 + w * 16 + c;
  const u16* qrow = qb + ((size_t)bh * 1024 + trow) * 64;
  bf16x8 qa0 = *(const bf16x8*)(qrow + g * 8);
  bf16x8 qa1 = *(const bf16x8*)(qrow + 32 + g * 8);
  float l_c = 0.f;
  f32x4 zero = {0.f, 0.f, 0.f, 0.f};
  f32x4 o_[4];
  #pragma unroll
  for (int nf = 0; nf < 4; ++nf) o_[nf] = zero;
  // staging addresses (row/c8 fixed per thread)
  int srow = tid >> 2, sc8 = (tid & 3) * 2;      // 256 threads cover 64 rows x 8 chunks... (2 chunks of 8 u16 each)
  // actually keep original decomposition: ci in [0,512): row=ci>>3, c8=ci&7
  // T14-lite double buffer: issue next tile's loads before compute.
  i32x4 rK[2], rU[2];
  #pragma unroll
  for (int p = 0; p < 2; ++p){
    int ci = tid + p * 256;
    int row = ci >> 3, c8 = ci & 7;
    rK[p] = *(const i32x4*)(qb + ((size_t)bh * 1024 + 0 + row) * 64 + c8 * 8);
    rU[p] = *(const i32x4*)(ubt + ((size_t)(bh * 64 + row)) * 1024 + 0 + c8 * 8);
  }
  for (int st = 0; st < 16; ++st){
    int s0 = st * 64;
    if (st) __syncthreads();   // prev tile's LDS reads done
    #pragma unroll
    for (int p = 0; p < 2; ++p){
      int ci = tid + p * 256;
      int row = ci >> 3, c8 = ci & 7;
      int dst = swz(row, c8 * 16);
      *(i32x4*)&Klds[dst] = rK[p];
      *(i32x4*)&Ulds[dst] = rU[p];
    }
    if (st < 15){
      int s1 = s0 + 64;
      #pragma unroll
      for (int p = 0; p < 2; ++p){
        int ci = tid + p * 256;
        int row = ci >> 3, c8 = ci & 7;
        rK[p] = *(const i32x4*)(qb + ((size_t)bh * 1024 + s1 + row) * 64 + c8 * 8);
        rU[p] = *(const i32x4*)(ubt + ((size_t)(bh * 64 + row)) * 1024 + s1 + c8 * 8);
      }
    }
    __syncthreads();
    f32x4 qs4[4];
    #pragma unroll
    for (int nf = 0; nf < 4; ++nf)
      qs4[nf] = *(const f32x4*)(qsq + (size_t)bh * 1024 + s0 + nf * 16 + g * 4);
    f32x4 sf[4];
    #pragma unroll
    for (int nf = 0; nf < 4; ++nf) sf[nf] = zero;
    #pragma unroll
    for (int nf = 0; nf < 4; ++nf){
      int krow = nf * 16 + c;
      bf16x8 kf0 = *(const bf16x8*)&Klds[swz(krow, g * 16)];
      bf16x8 kf1 = *(const bf16x8*)&Klds[swz(krow, 64 + g * 16)];
      // swapped: A = K rows (s), B = Q rows (t) -> C[row=g*4+r -> s][col=c -> t]
      sf[nf] = __builtin_amdgcn_mfma_f32_16x16x32_bf16(kf0, qa0, sf[nf], 0, 0, 0);
      sf[nf] = __builtin_amdgcn_mfma_f32_16x16x32_bf16(kf1, qa1, sf[nf], 0, 0, 0);
    }
    // p = 2^(S*C1 - qsq_s_scaled), t=c fixed per lane -> l is lane-local
    #pragma unroll
    for (int nf = 0; nf < 4; ++nf){
      float p0 = exp2f(fmaf(sf[nf][0], C1, -qs4[nf][0]));
      float p1 = exp2f(fmaf(sf[nf][1], C1, -qs4[nf][1]));
      float p2 = exp2f(fmaf(sf[nf][2], C1, -qs4[nf][2]));
      float p3 = exp2f(fmaf(sf[nf][3], C1, -qs4[nf][3]));
      l_c += (p0 + p1) + (p2 + p3);
      u32x2 pk;
      pk[0] = ((u32)f2bf_fast(p1) << 16) | (u32)f2bf_fast(p0);
      pk[1] = ((u32)f2bf_fast(p3) << 16) | (u32)f2bf_fast(p2);
      *(u32x2*)&Plds[w][c * 72 + nf * 16 + g * 4] = pk;
    }
    // PV: A = P[t=c][s], B = U rows (e)
    #pragma unroll
    for (int kk = 0; kk < 2; ++kk){
      bf16x8 pa = *(const bf16x8*)&Plds[w][c * 72 + kk * 32 + g * 8];
      #pragma unroll
      for (int nf = 0; nf < 4; ++nf){
        int urow = nf * 16 + c;
        bf16x8 uf = *(const bf16x8*)&Ulds[swz(urow, kk * 64 + g * 16)];
        o_[nf] = __builtin_amdgcn_mfma_f32_16x16x32_bf16(pa, uf, o_[nf], 0, 0, 0);
      }
    }
  }
  // total l for t=c: reduce across the 4 g-groups
  l_c += __shfl_xor(l_c, 16);
  l_c += __shfl_xor(l_c, 32);
  // redistribute: output rows are t = w*16 + g*4 + r -> need l from lane (g*4+r)
  float inv[4];
  #pragma unroll
  for (int r = 0; r < 4; ++r)
    inv[r] = 1.0f / __shfl(l_c, g * 4 + r);
  #pragma unroll
  for (int nf = 0; nf < 4; ++nf)
    #pragma unroll
    for (int r = 0; r < 4; ++r){
      int t = tt * 64 + w * 16 + g * 4 + r;
      int dd = nf * 16 + c;
      obm[((size_t)(t * 8 + b)) * 1024 + h * 64 + dd] = f2bf(o_[nf][r] * inv[r]);
    }
}

extern "C" void kernel_launch(void* const* d_in, const int* in_sizes, int n_in,
                              void* d_out, int out_size, void* d_ws, size_t ws_size,
                              hipStream_t stream) {
  const float* x   = (const float*)d_in[0];
  const float* qw  = (const float*)d_in[1];
  const float* vw  = (const float*)d_in[2];
  const float* ow  = (const float*)d_in[3];
  const float* ob_bias = (const float*)d_in[4];
  float* out = (float*)d_out;

  // d_out (32 MiB) doubles as scratch:
  //  - Bp partials (2 MiB) live at d_out front, consumed by k_bred before gemm1 writes qb there
  //  - qb (16 MiB) + ubt (16 MiB) fill it afterwards; all dead before gemm2 writes `out`.
  float* Bp = (float*)d_out;
  u16* qb  = (u16*)d_out;                                     // [bh][t][d]  16 MiB
  u16* ubt = (u16*)((char*)d_out + (size_t)16 * 1024 * 1024); // [bh][d][t]  16 MiB

  char* ws = (char*)d_ws;
  size_t off = 0;
  auto alloc = [&](size_t bytes) -> void* {
    void* p = ws + off;
    off += (bytes + 255) & ~(size_t)255;
    return p;
  };
  u16*   wqt = (u16*)  alloc((size_t)1024 * 1024 * 2);   // Wq^T bf16 [n][m]   2 MiB
  u16*   obm = (u16*)  alloc((size_t)8192 * 1024 * 2);   // attn out bf16     16 MiB
  float* qsq = (float*)alloc((size_t)128 * 1024 * 4);    // scaled |q|^2     0.5 MiB
  u16*   Bt  = (u16*)  alloc((size_t)16 * 64 * 64 * 2);  // B_h^T bf16      0.125 MiB

  k_bmatp<<<128, 256, 0, stream>>>(qw, vw, Bp);
  k_bred<<<256, 256, 0, stream>>>(Bp, Bt);
  k_wqt<<<dim3(16, 16), 256, 0, stream>>>(qw, wqt);
  // GEMM1: q = x @ Wq  (A = x f32 cast-on-stage, B = Wq^T bf16) -> qb scatter
  k_gemm<1, 0, 0><<<512, 256, 0, stream>>>(x, wqt, qb, nullptr, 8192, 1024, 1024);
  k_u<<<2048, 64, 0, stream>>>(qb, Bt, ubt, qsq);
  k_attn<<<2048, 256, 0, stream>>>(qb, ubt, qsq, obm);
  // GEMM2: out = obm @ out_w^T + b  (A = obm bf16, B = out_w f32 cast-on-stage)
  k_gemm<0, 1, 1><<<512, 256, 0, stream>>>(obm, ow, out, ob_bias, 8192, 1024, 1024);
}

// Round 6
// 153.827 us; speedup vs baseline: 1.9610x; 1.0153x over previous
//
#include <hip/hip_runtime.h>
#include <hip/hip_bf16.h>

#define T_ 1024
#define N_ 8
#define D_ 1024
#define H_ 16
#define HD_ 64

typedef __attribute__((ext_vector_type(8))) short bf16x8;
typedef __attribute__((ext_vector_type(4))) float f32x4;
typedef __attribute__((ext_vector_type(4))) int i32x4;
typedef __attribute__((ext_vector_type(2))) unsigned int u32x2;
typedef unsigned short u16;
typedef unsigned int u32;

__device__ __forceinline__ float bf2f(u16 u){
  union { float f; unsigned int i; } v; v.i = ((unsigned int)u) << 16; return v.f;
}
__device__ __forceinline__ u16 f2bf(float f){
  union { float f; unsigned int i; } v; v.f = f;
  unsigned int r = v.i + 0x7FFFu + ((v.i >> 16) & 1u);
  return (u16)(r >> 16);
}
__device__ __forceinline__ u16 f2bf_fast(float f){
  __hip_bfloat16 h = __float2bfloat16(f);   // RNE; compiler packs pairs into v_cvt_pk_bf16_f32
  return *reinterpret_cast<u16*>(&h);
}

// ---------------- transpose+cast Wq (D x D) -> Wqt[n][m] bf16 ----------------
__global__ __launch_bounds__(256) void k_wqt(const float* __restrict__ Wq, u16* __restrict__ Wqt){
  __shared__ float tld[64][65];
  int m0 = blockIdx.x * 64, n0 = blockIdx.y * 64;
  int col = threadIdx.x & 63, rq = threadIdx.x >> 6;
  #pragma unroll
  for (int p = 0; p < 16; ++p){
    int row = rq * 16 + p;
    tld[row][col] = Wq[(size_t)(m0 + row) * D_ + n0 + col];
  }
  __syncthreads();
  #pragma unroll
  for (int p = 0; p < 16; ++p){
    int row = rq * 16 + p;
    Wqt[(size_t)(n0 + row) * D_ + m0 + col] = f2bf(tld[col][row]);
  }
}

// ---------------- Bp[sp][h][d][e] partials of sum_m qw[m,h,e]*vw[m,h,d] (MFMA split-K) ----------------
__global__ __launch_bounds__(256) void k_bmatp(const float* __restrict__ qw, const float* __restrict__ vw,
                                               float* __restrict__ Bp){
  int h = (int)blockIdx.x >> 3, sp = (int)blockIdx.x & 7;
  int tid = threadIdx.x, lane = tid & 63, w = tid >> 6;
  int g = lane >> 4, c = lane & 15;
  __shared__ u16 Qt[64 * 72];  // [e][m] transposed, bf16
  __shared__ u16 Vt[64 * 72];  // [d][m]
  f32x4 zero = {0.f, 0.f, 0.f, 0.f};
  f32x4 acc[4];
  #pragma unroll
  for (int eb = 0; eb < 4; ++eb) acc[eb] = zero;
  int m = tid >> 2, cg = tid & 3;
  for (int mt = sp * 128; mt < sp * 128 + 128; mt += 64){
    __syncthreads();
    #pragma unroll
    for (int q = 0; q < 4; ++q){
      int e0 = cg * 16 + q * 4;
      f32x4 vq = *(const f32x4*)(qw + (size_t)(mt + m) * D_ + h * 64 + e0);
      f32x4 vv = *(const f32x4*)(vw + (size_t)(mt + m) * D_ + h * 64 + e0);
      #pragma unroll
      for (int j = 0; j < 4; ++j){
        Qt[(e0 + j) * 72 + m] = f2bf_fast(vq[j]);
        Vt[(e0 + j) * 72 + m] = f2bf_fast(vv[j]);
      }
    }
    __syncthreads();
    #pragma unroll
    for (int kk = 0; kk < 2; ++kk){
      bf16x8 av = *(const bf16x8*)&Vt[(w * 16 + c) * 72 + kk * 32 + g * 8];
      #pragma unroll
      for (int eb = 0; eb < 4; ++eb){
        bf16x8 bq = *(const bf16x8*)&Qt[(eb * 16 + c) * 72 + kk * 32 + g * 8];
        acc[eb] = __builtin_amdgcn_mfma_f32_16x16x32_bf16(av, bq, acc[eb], 0, 0, 0);
      }
    }
  }
  #pragma unroll
  for (int eb = 0; eb < 4; ++eb)
    #pragma unroll
    for (int r = 0; r < 4; ++r){
      int d = w * 16 + g * 4 + r, e = eb * 16 + c;
      Bp[(((size_t)sp * 16 + h) * 64 + d) * 64 + e] = acc[eb][r];
    }
}

// ---------------- reduce 8 partials -> Bt bf16 ----------------
__global__ __launch_bounds__(256) void k_bred(const float* __restrict__ Bp, u16* __restrict__ Bt){
  int i = blockIdx.x * 256 + threadIdx.x;   // 65536 total
  float s = 0.f;
  #pragma unroll
  for (int j = 0; j < 8; ++j) s += Bp[(size_t)j * 65536 + i];
  Bt[i] = f2bf(s * 0.125f);
}

// swizzled u16-index within a [rows][64] u16 LDS tile: XOR byte-bits 4-6 with row&7
__device__ __forceinline__ int swz(int row, int colbyte){
  return row * 64 + (((colbyte) ^ ((row & 7) << 4)) >> 1);
}

// ---------------- 128x128 bf16 MFMA GEMM, A[MxK] @ B^T (B given [N][K]) ----------------
template<int A_F32, int B_F32, int EPI>
__global__ __launch_bounds__(256) void k_gemm(const void* __restrict__ A_, const void* __restrict__ B_,
                                              void* __restrict__ Cv, const float* __restrict__ bias,
                                              int M, int N, int K){
  int nbn = N >> 7;
  int ii = (int)blockIdx.x;
  int sw = (ii & 7) * 64 + (ii >> 3);      // XCD-contiguous chunks (512 = 8*64 blocks)
  int bm = sw / nbn, bn = sw % nbn;
  int tid = threadIdx.x, lane = tid & 63, wid = tid >> 6;
  int wr = wid >> 1, wc = wid & 1, g = lane >> 4, c = lane & 15;
  __shared__ u16 As[128 * 64];
  __shared__ u16 Bs[128 * 64];
  f32x4 zero = {0.f, 0.f, 0.f, 0.f};
  f32x4 acc[4][4];
  #pragma unroll
  for (int m = 0; m < 4; ++m)
    #pragma unroll
    for (int n = 0; n < 4; ++n) acc[m][n] = zero;
  for (int kt = 0; kt < K; kt += 64){
    __syncthreads();
    #pragma unroll
    for (int p = 0; p < 4; ++p){
      int ci = tid + p * 256;
      int row = ci >> 3, c8 = ci & 7;
      int dst = swz(row, c8 * 16);
      if (A_F32){
        const float* A = (const float*)A_;
        const float* src = A + (size_t)(bm * 128 + row) * K + kt + c8 * 8;
        f32x4 v0 = *(const f32x4*)src;
        f32x4 v1 = *(const f32x4*)(src + 4);
        union { u16 u[8]; i32x4 v; } pk;
        #pragma unroll
        for (int j = 0; j < 4; ++j){ pk.u[j] = f2bf_fast(v0[j]); pk.u[4 + j] = f2bf_fast(v1[j]); }
        *(i32x4*)&As[dst] = pk.v;
      } else {
        const u16* A = (const u16*)A_;
        *(i32x4*)&As[dst] = *(const i32x4*)(A + (size_t)(bm * 128 + row) * K + kt + c8 * 8);
      }
      if (B_F32){
        const float* B = (const float*)B_;
        const float* src = B + (size_t)(bn * 128 + row) * K + kt + c8 * 8;
        f32x4 v0 = *(const f32x4*)src;
        f32x4 v1 = *(const f32x4*)(src + 4);
        union { u16 u[8]; i32x4 v; } pk;
        #pragma unroll
        for (int j = 0; j < 4; ++j){ pk.u[j] = f2bf_fast(v0[j]); pk.u[4 + j] = f2bf_fast(v1[j]); }
        *(i32x4*)&Bs[dst] = pk.v;
      } else {
        const u16* B = (const u16*)B_;
        *(i32x4*)&Bs[dst] = *(const i32x4*)(B + (size_t)(bn * 128 + row) * K + kt + c8 * 8);
      }
    }
    __syncthreads();
    #pragma unroll
    for (int kk = 0; kk < 2; ++kk){
      bf16x8 af[4], bfr[4];
      #pragma unroll
      for (int m = 0; m < 4; ++m){
        int row = wr * 64 + m * 16 + c;
        af[m] = *(const bf16x8*)&As[swz(row, kk * 64 + g * 16)];
      }
      #pragma unroll
      for (int n = 0; n < 4; ++n){
        int row = wc * 64 + n * 16 + c;
        bfr[n] = *(const bf16x8*)&Bs[swz(row, kk * 64 + g * 16)];
      }
      #pragma unroll
      for (int m = 0; m < 4; ++m)
        #pragma unroll
        for (int n = 0; n < 4; ++n)
          acc[m][n] = __builtin_amdgcn_mfma_f32_16x16x32_bf16(af[m], bfr[n], acc[m][n], 0, 0, 0);
    }
  }
  #pragma unroll
  for (int m = 0; m < 4; ++m)
    #pragma unroll
    for (int n = 0; n < 4; ++n)
      #pragma unroll
      for (int r = 0; r < 4; ++r){
        int row = bm * 128 + wr * 64 + m * 16 + g * 4 + r;
        int col = bn * 128 + wc * 64 + n * 16 + c;
        float v = acc[m][n][r];
        if (EPI == 0){
          int t = row >> 3, b = row & 7, hh = col >> 6, dd = col & 63;
          ((u16*)Cv)[(((size_t)(b * H_ + hh)) * T_ + t) * HD_ + dd] = f2bf(v);
        } else {
          ((float*)Cv)[(size_t)row * N + col] = v + bias[col];
        }
      }
}

// ---------------- u^T = B_h^T q^T per (bh, 64-t tile); also scaled q_sq. 1 wave. ----------------
__global__ __launch_bounds__(64) void k_u(const u16* __restrict__ qb, const u16* __restrict__ Bt,
                                          u16* __restrict__ ubt, float* __restrict__ qsq){
  int bh = blockIdx.x >> 4, tt = blockIdx.x & 15;
  int h = bh & 15, t0 = tt * 64;
  int lane = threadIdx.x, g = lane >> 4, c = lane & 15;
  const float QS_SCALE = 0.125f * 1.44269504088896340736f;
  bf16x8 af[4][2], bq[4][2];
  #pragma unroll
  for (int mf = 0; mf < 4; ++mf)
    #pragma unroll
    for (int kk = 0; kk < 2; ++kk)
      af[mf][kk] = *(const bf16x8*)(Bt + ((size_t)(h * 64 + mf * 16 + c)) * 64 + kk * 32 + g * 8);
  #pragma unroll
  for (int nf = 0; nf < 4; ++nf)
    #pragma unroll
    for (int kk = 0; kk < 2; ++kk)
      bq[nf][kk] = *(const bf16x8*)(qb + ((size_t)(bh * 1024 + t0 + nf * 16 + c)) * 64 + kk * 32 + g * 8);
  // q_sq from the same bf16 q; prescaled by 0.125*log2(e)
  #pragma unroll
  for (int nf = 0; nf < 4; ++nf){
    float ss = 0.f;
    #pragma unroll
    for (int kk = 0; kk < 2; ++kk)
      #pragma unroll
      for (int j = 0; j < 8; ++j){ float f = bf2f((u16)bq[nf][kk][j]); ss = fmaf(f, f, ss); }
    ss += __shfl_xor(ss, 16);
    ss += __shfl_xor(ss, 32);
    if (lane < 16) qsq[(size_t)bh * 1024 + t0 + nf * 16 + lane] = ss * QS_SCALE;
  }
  f32x4 zero = {0.f, 0.f, 0.f, 0.f};
  f32x4 acc[4][4];
  #pragma unroll
  for (int mf = 0; mf < 4; ++mf)
    #pragma unroll
    for (int nf = 0; nf < 4; ++nf) acc[mf][nf] = zero;
  #pragma unroll
  for (int kk = 0; kk < 2; ++kk)
    #pragma unroll
    for (int mf = 0; mf < 4; ++mf)
      #pragma unroll
      for (int nf = 0; nf < 4; ++nf)
        acc[mf][nf] = __builtin_amdgcn_mfma_f32_16x16x32_bf16(af[mf][kk], bq[nf][kk], acc[mf][nf], 0, 0, 0);
  #pragma unroll
  for (int mf = 0; mf < 4; ++mf)
    #pragma unroll
    for (int nf = 0; nf < 4; ++nf)
      #pragma unroll
      for (int r = 0; r < 4; ++r)
        ubt[((size_t)(bh * 64 + mf * 16 + g * 4 + r)) * 1024 + t0 + nf * 16 + c] = f2bf(acc[mf][nf][r]);
}

// ---------------- flash-style L2 attention, fixed-max softmax, TBLK=128 ----------------
// Block: (bh, 128-row t tile); 4 waves x 32 t-rows each. K/U tiles (64 s) are
// staged once per round and amortized over 128 t-rows (1.8x less LDS/flop).
// Swapped QK^T: sf[sb][ta] = mfma(K, Q) -> lane (c,g) holds P[s=sb*16+g*4+r][t=ta*16+c].
// P round-trips per-wave LDS [32 t][72 u16 rows] (64 s + 8 pad): 8 ds_write_b64 -> 4 ds_read_b128.
__global__ __launch_bounds__(256) void k_attn(const u16* __restrict__ qb, const u16* __restrict__ ubt,
                                              const float* __restrict__ qsq, u16* __restrict__ obm){
  int i = (int)blockIdx.x;
  // XCD grouping: XCD (i&7) gets bh in [16*(i&7), 16*(i&7)+16), all 8 t-tiles.
  int bh = ((i & 7) << 4) + (i >> 6);
  int tt = (i >> 3) & 7;
  int b = bh >> 4, h = bh & 15;
  int tid = threadIdx.x, w = tid >> 6, lane = tid & 63;
  int g = lane >> 4, c = lane & 15;
  __shared__ u16 Klds[64 * 64];
  __shared__ u16 Ulds[64 * 64];
  __shared__ u16 Plds[4][32 * 72];   // per-wave [32 t][72 u16] (64 s + 8 pad)
  const float L2E = 1.44269504088896340736f;
  const float C1 = 0.25f * L2E;
  int t0 = tt * 128 + w * 32;
  // Q fragments for this wave's 32 t-rows
  bf16x8 qa[2][2];
  #pragma unroll
  for (int ta = 0; ta < 2; ++ta)
    #pragma unroll
    for (int kk = 0; kk < 2; ++kk)
      qa[ta][kk] = *(const bf16x8*)(qb + ((size_t)bh * 1024 + t0 + ta * 16 + c) * 64 + kk * 32 + g * 8);
  float l_[2] = {0.f, 0.f};
  f32x4 zero = {0.f, 0.f, 0.f, 0.f};
  f32x4 o_[2][4];
  #pragma unroll
  for (int ta = 0; ta < 2; ++ta)
    #pragma unroll
    for (int nf = 0; nf < 4; ++nf) o_[ta][nf] = zero;
  // T14 prefetch: issue next tile's global loads before compute
  i32x4 rK[2], rU[2];
  #pragma unroll
  for (int p = 0; p < 2; ++p){
    int ci = tid + p * 256;
    int row = ci >> 3, c8 = ci & 7;
    rK[p] = *(const i32x4*)(qb + ((size_t)bh * 1024 + row) * 64 + c8 * 8);
    rU[p] = *(const i32x4*)(ubt + ((size_t)(bh * 64 + row)) * 1024 + c8 * 8);
  }
  for (int st = 0; st < 16; ++st){
    int s0 = st * 64;
    if (st) __syncthreads();   // prev round's LDS reads done
    #pragma unroll
    for (int p = 0; p < 2; ++p){
      int ci = tid + p * 256;
      int row = ci >> 3, c8 = ci & 7;
      int dst = swz(row, c8 * 16);
      *(i32x4*)&Klds[dst] = rK[p];
      *(i32x4*)&Ulds[dst] = rU[p];
    }
    if (st < 15){
      int s1 = s0 + 64;
      #pragma unroll
      for (int p = 0; p < 2; ++p){
        int ci = tid + p * 256;
        int row = ci >> 3, c8 = ci & 7;
        rK[p] = *(const i32x4*)(qb + ((size_t)bh * 1024 + s1 + row) * 64 + c8 * 8);
        rU[p] = *(const i32x4*)(ubt + ((size_t)(bh * 64 + row)) * 1024 + s1 + c8 * 8);
      }
    }
    __syncthreads();
    f32x4 qs4[4];
    #pragma unroll
    for (int sb = 0; sb < 4; ++sb)
      qs4[sb] = *(const f32x4*)(qsq + (size_t)bh * 1024 + s0 + sb * 16 + g * 4);
    f32x4 sf[4][2];
    #pragma unroll
    for (int sb = 0; sb < 4; ++sb)
      #pragma unroll
      for (int ta = 0; ta < 2; ++ta) sf[sb][ta] = zero;
    __builtin_amdgcn_s_setprio(1);
    #pragma unroll
    for (int sb = 0; sb < 4; ++sb){
      int krow = sb * 16 + c;
      bf16x8 kf0 = *(const bf16x8*)&Klds[swz(krow, g * 16)];
      bf16x8 kf1 = *(const bf16x8*)&Klds[swz(krow, 64 + g * 16)];
      #pragma unroll
      for (int ta = 0; ta < 2; ++ta){
        sf[sb][ta] = __builtin_amdgcn_mfma_f32_16x16x32_bf16(kf0, qa[ta][0], sf[sb][ta], 0, 0, 0);
        sf[sb][ta] = __builtin_amdgcn_mfma_f32_16x16x32_bf16(kf1, qa[ta][1], sf[sb][ta], 0, 0, 0);
      }
    }
    __builtin_amdgcn_s_setprio(0);
    // p = 2^(S*C1 - qsq_s_scaled); write P to per-wave [t][s] LDS (s-contiguous b64)
    #pragma unroll
    for (int ta = 0; ta < 2; ++ta)
      #pragma unroll
      for (int sb = 0; sb < 4; ++sb){
        float p0 = exp2f(fmaf(sf[sb][ta][0], C1, -qs4[sb][0]));
        float p1 = exp2f(fmaf(sf[sb][ta][1], C1, -qs4[sb][1]));
        float p2 = exp2f(fmaf(sf[sb][ta][2], C1, -qs4[sb][2]));
        float p3 = exp2f(fmaf(sf[sb][ta][3], C1, -qs4[sb][3]));
        l_[ta] += (p0 + p1) + (p2 + p3);
        u32x2 pk;
        pk[0] = ((u32)f2bf_fast(p1) << 16) | (u32)f2bf_fast(p0);
        pk[1] = ((u32)f2bf_fast(p3) << 16) | (u32)f2bf_fast(p2);
        *(u32x2*)&Plds[w][(ta * 16 + c) * 72 + sb * 16 + g * 4] = pk;
      }
    // PV: A = P[t][s] (b128 rows), B = U^T rows (e')
    __builtin_amdgcn_s_setprio(1);
    #pragma unroll
    for (int kch = 0; kch < 2; ++kch){
      bf16x8 pa[2];
      #pragma unroll
      for (int ta = 0; ta < 2; ++ta)
        pa[ta] = *(const bf16x8*)&Plds[w][(ta * 16 + c) * 72 + kch * 32 + g * 8];
      #pragma unroll
      for (int nf = 0; nf < 4; ++nf){
        bf16x8 uf = *(const bf16x8*)&Ulds[swz(nf * 16 + c, kch * 64 + g * 16)];
        #pragma unroll
        for (int ta = 0; ta < 2; ++ta)
          o_[ta][nf] = __builtin_amdgcn_mfma_f32_16x16x32_bf16(pa[ta], uf, o_[ta][nf], 0, 0, 0);
      }
    }
    __builtin_amdgcn_s_setprio(0);
  }
  // l reduce across g-groups, then redistribute to output rows
  #pragma unroll
  for (int ta = 0; ta < 2; ++ta){
    l_[ta] += __shfl_xor(l_[ta], 16);
    l_[ta] += __shfl_xor(l_[ta], 32);
  }
  float inv[2][4];
  #pragma unroll
  for (int ta = 0; ta < 2; ++ta)
    #pragma unroll
    for (int r = 0; r < 4; ++r)
      inv[ta][r] = 1.0f / __shfl(l_[ta], g * 4 + r);
  #pragma unroll
  for (int ta = 0; ta < 2; ++ta)
    #pragma unroll
    for (int nf = 0; nf < 4; ++nf)
      #pragma unroll
      for (int r = 0; r < 4; ++r){
        int t = t0 + ta * 16 + g * 4 + r;
        int dd = nf * 16 + c;
        obm[((size_t)(t * 8 + b)) * 1024 + h * 64 + dd] = f2bf(o_[ta][nf][r] * inv[ta][r]);
      }
}

extern "C" void kernel_launch(void* const* d_in, const int* in_sizes, int n_in,
                              void* d_out, int out_size, void* d_ws, size_t ws_size,
                              hipStream_t stream) {
  const float* x   = (const float*)d_in[0];
  const float* qw  = (const float*)d_in[1];
  const float* vw  = (const float*)d_in[2];
  const float* ow  = (const float*)d_in[3];
  const float* ob_bias = (const float*)d_in[4];
  float* out = (float*)d_out;

  // d_out (32 MiB) doubles as scratch:
  //  - Bp partials (2 MiB) live at d_out front, consumed by k_bred before gemm1 writes qb there
  //  - qb (16 MiB) + ubt (16 MiB) fill it afterwards; all dead before gemm2 writes `out`.
  float* Bp = (float*)d_out;
  u16* qb  = (u16*)d_out;                                     // [bh][t][d]  16 MiB
  u16* ubt = (u16*)((char*)d_out + (size_t)16 * 1024 * 1024); // [bh][d][t]  16 MiB

  char* ws = (char*)d_ws;
  size_t off = 0;
  auto alloc = [&](size_t bytes) -> void* {
    void* p = ws + off;
    off += (bytes + 255) & ~(size_t)255;
    return p;
  };
  u16*   wqt = (u16*)  alloc((size_t)1024 * 1024 * 2);   // Wq^T bf16 [n][m]   2 MiB
  u16*   obm = (u16*)  alloc((size_t)8192 * 1024 * 2);   // attn out bf16     16 MiB
  float* qsq = (float*)alloc((size_t)128 * 1024 * 4);    // scaled |q|^2     0.5 MiB
  u16*   Bt  = (u16*)  alloc((size_t)16 * 64 * 64 * 2);  // B_h^T bf16      0.125 MiB

  k_bmatp<<<128, 256, 0, stream>>>(qw, vw, Bp);
  k_bred<<<256, 256, 0, stream>>>(Bp, Bt);
  k_wqt<<<dim3(16, 16), 256, 0, stream>>>(qw, wqt);
  // GEMM1: q = x @ Wq  (A = x f32 cast-on-stage, B = Wq^T bf16) -> qb scatter
  k_gemm<1, 0, 0><<<512, 256, 0, stream>>>(x, wqt, qb, nullptr, 8192, 1024, 1024);
  k_u<<<2048, 64, 0, stream>>>(qb, Bt, ubt, qsq);
  k_attn<<<1024, 256, 0, stream>>>(qb, ubt, qsq, obm);
  // GEMM2: out = obm @ out_w^T + b  (A = obm bf16, B = out_w f32 cast-on-stage)
  k_gemm<0, 1, 1><<<512, 256, 0, stream>>>(obm, ow, out, ob_bias, 8192, 1024, 1024);
}